// Round 1
// baseline (435.118 us; speedup 1.0000x reference)
//
#include <hip/hip_runtime.h>

#define NB 8
#define NC 256
#define ND 32
#define NN 16384
#define EPSF 1e-6f

__device__ __forceinline__ float softplusf(float v) {
    // stable log1p(exp(v))
    return fmaxf(v, 0.0f) + log1pf(__expf(-fabsf(v)));
}

// ---------------------------------------------------------------------------
// Kernel A: per (b, 256-col tile): K = softplus(wk@x + bk); accumulate
//   KX[m][e] = sum_n K[m][n]*x[e][n]  (partials per block) and Ksum[m].
// block = 256 threads, grid = 8*64 = 512. LDS ~71 KB -> 2 blocks/CU.
// ---------------------------------------------------------------------------
__global__ __launch_bounds__(256) void kA(
    const float* __restrict__ x, const float* __restrict__ wk,
    const float* __restrict__ bk, float* __restrict__ part,
    float* __restrict__ kxf, float* __restrict__ ksum, int use_part)
{
    __shared__ __align__(16) float xsT[32 * 258];  // [j][c], pad 2: b64-aligned, <=2-way banks
    __shared__ __align__(16) float wkM[32 * 260];  // [m][c], pad 4: b128-aligned
    __shared__ __align__(16) float Ks [32 * 36];   // [j][m], pad 4: b128-aligned

    const int t    = threadIdx.x;
    const int b    = blockIdx.x >> 6;
    const int tile = blockIdx.x & 63;
    const int n0   = tile << 8;                    // 256 columns per block
    const float* xb = x + (size_t)b * NC * NN;

    // stage wk as wkM[m][c] (coalesced read)
    #pragma unroll
    for (int i = 0; i < 32; ++i) {
        int f = t + (i << 8);
        wkM[(f >> 8) * 260 + (f & 255)] = wk[f];
    }

    const int jA  = t & 31;          // K-compute: column j
    const int m0A = (t >> 5) << 2;   // K-compute: 4 m's
    const int m0X = (t >> 6) << 3;   // KX: 8 m's
    const int eX  = t & 63;          // KX: e base (4 e's: eX + 64k)

    float bkr[4];
    #pragma unroll
    for (int r = 0; r < 4; ++r) bkr[r] = bk[m0A + r];

    float acc[8][4];
    #pragma unroll
    for (int a = 0; a < 8; ++a)
        #pragma unroll
        for (int kk = 0; kk < 4; ++kk) acc[a][kk] = 0.0f;
    float ksacc[4] = {0.f, 0.f, 0.f, 0.f};

    for (int st = 0; st < 8; ++st) {
        const int n1 = n0 + (st << 5);
        __syncthreads();  // xsT free from previous iter's KX readers (covers wkM on st=0)
        // stage 256x32 x sub-tile, transposed: xsT[j][c]
        #pragma unroll
        for (int i = 0; i < 32; ++i) {
            int f = t + (i << 8);
            int c = f >> 5, j = f & 31;
            xsT[j * 258 + c] = xb[c * NN + n1 + j];
        }
        __syncthreads();

        // --- K compute: K[m0A..+3][jA] ---
        float kacc[4] = {0.f, 0.f, 0.f, 0.f};
        #pragma unroll 4
        for (int c = 0; c < 256; c += 4) {
            float2 xa = *(const float2*)&xsT[jA * 258 + c];
            float2 xc = *(const float2*)&xsT[jA * 258 + c + 2];
            #pragma unroll
            for (int r = 0; r < 4; ++r) {
                float4 w = *(const float4*)&wkM[(m0A + r) * 260 + c];
                kacc[r] = fmaf(xa.x, w.x, kacc[r]);
                kacc[r] = fmaf(xa.y, w.y, kacc[r]);
                kacc[r] = fmaf(xc.x, w.z, kacc[r]);
                kacc[r] = fmaf(xc.y, w.w, kacc[r]);
            }
        }
        #pragma unroll
        for (int r = 0; r < 4; ++r) {
            float kv_ = softplusf(kacc[r] + bkr[r]);
            Ks[jA * 36 + m0A + r] = kv_;
            ksacc[r] += kv_;
        }
        __syncthreads();

        // --- KX accumulate: acc[a][kk] += K[m0X+a][j] * x[eX+64kk][j] ---
        #pragma unroll 2
        for (int j = 0; j < 32; ++j) {
            const float* kp = &Ks[j * 36 + m0X];
            float4 ka = *(const float4*)kp;        // wave-uniform broadcast
            float4 kb = *(const float4*)(kp + 4);
            const float km[8] = {ka.x, ka.y, ka.z, ka.w, kb.x, kb.y, kb.z, kb.w};
            float xv[4];
            #pragma unroll
            for (int kk = 0; kk < 4; ++kk) xv[kk] = xsT[j * 258 + eX + (kk << 6)];
            #pragma unroll
            for (int a = 0; a < 8; ++a)
                #pragma unroll
                for (int kk = 0; kk < 4; ++kk)
                    acc[a][kk] = fmaf(km[a], xv[kk], acc[a][kk]);
        }
    }

    // Ksum: reduce over jA (lanes 0..31 within each 32-lane slot group)
    #pragma unroll
    for (int r = 0; r < 4; ++r) {
        float v = ksacc[r];
        for (int o = 16; o; o >>= 1) v += __shfl_down(v, o, 32);
        if (jA == 0) atomicAdd(&ksum[b * 32 + m0A + r], v);
    }

    // KX epilogue
    if (use_part) {
        float* dst = part + (size_t)blockIdx.x * 8192;
        #pragma unroll
        for (int a = 0; a < 8; ++a)
            #pragma unroll
            for (int kk = 0; kk < 4; ++kk)
                dst[(m0X + a) * 256 + eX + (kk << 6)] = acc[a][kk];
    } else {
        float* dst = kxf + (size_t)b * 8192;
        #pragma unroll
        for (int a = 0; a < 8; ++a)
            #pragma unroll
            for (int kk = 0; kk < 4; ++kk)
                atomicAdd(&dst[(m0X + a) * 256 + eX + (kk << 6)], acc[a][kk]);
    }
}

// ---------------------------------------------------------------------------
// Kernel R: reduce 64 tile-partials per batch -> KX final. grid 256 x 256.
// ---------------------------------------------------------------------------
__global__ __launch_bounds__(256) void kR(const float* __restrict__ part,
                                          float* __restrict__ kxf)
{
    int idx = blockIdx.x * 256 + threadIdx.x;   // [0, 8*8192)
    int b = idx >> 13, f = idx & 8191;
    float s = 0.f;
    #pragma unroll 8
    for (int tl = 0; tl < 64; ++tl)
        s += part[(size_t)(b * 64 + tl) * 8192 + f];
    kxf[idx] = s;
}

// ---------------------------------------------------------------------------
// Kernel B: KV[m][c] = sum_e KX[m][e]*wv[c][e] + bv[c]*Ksum[m].
// grid 64 = 8b x 8 c-groups of 32; 256 threads.
// ---------------------------------------------------------------------------
__global__ __launch_bounds__(256) void kB(
    const float* __restrict__ kxf, const float* __restrict__ ksum,
    const float* __restrict__ wv, const float* __restrict__ bv,
    float* __restrict__ kv)
{
    __shared__ float wvT[256 * 33];  // [e][cl]
    __shared__ float kxs[32 * 257];  // [m][e]

    const int t  = threadIdx.x;
    const int b  = blockIdx.x >> 3;
    const int c0 = (blockIdx.x & 7) << 5;

    #pragma unroll
    for (int i = 0; i < 32; ++i) {
        int f = t + (i << 8);
        int r = f >> 8, e = f & 255;
        wvT[e * 33 + r]  = wv[(size_t)(c0 + r) * 256 + e];
        kxs[r * 257 + e] = kxf[b * 8192 + f];
    }
    __syncthreads();

    const int cl = t & 31, mq = t >> 5;
    float a0 = 0.f, a1 = 0.f, a2 = 0.f, a3 = 0.f;
    for (int e = 0; e < 256; ++e) {
        float wvv = wvT[e * 33 + cl];
        a0 = fmaf(kxs[(mq     ) * 257 + e], wvv, a0);
        a1 = fmaf(kxs[(mq +  8) * 257 + e], wvv, a1);
        a2 = fmaf(kxs[(mq + 16) * 257 + e], wvv, a2);
        a3 = fmaf(kxs[(mq + 24) * 257 + e], wvv, a3);
    }
    const int c = c0 + cl;
    const float bvc = bv[c];
    const float* ks = ksum + b * 32;
    float* kvb = kv + (size_t)b * 8192;
    kvb[(mq     ) * 256 + c] = a0 + bvc * ks[mq     ];
    kvb[(mq +  8) * 256 + c] = a1 + bvc * ks[mq +  8];
    kvb[(mq + 16) * 256 + c] = a2 + bvc * ks[mq + 16];
    kvb[(mq + 24) * 256 + c] = a3 + bvc * ks[mq + 24];
}

// ---------------------------------------------------------------------------
// Kernel C: Q = softplus(wq@x + bq); den = Q.(Ksum+EPS);
//   out[c][n] = x[c][n] + (gamma/den) * sum_m Q[m][n]*KV[m][c].
// grid 512 (b, 256-col tile), 512 threads, J=64 sub-tiles. LDS ~140 KB.
// ---------------------------------------------------------------------------
__global__ __launch_bounds__(512) void kC(
    const float* __restrict__ x, const float* __restrict__ wq,
    const float* __restrict__ bq, const float* __restrict__ kv,
    const float* __restrict__ ksum, const float* __restrict__ gamma,
    float* __restrict__ out)
{
    __shared__ __align__(16) float xs [256 * 64];  // [c][j]
    __shared__ __align__(16) float wqM[32 * 260];  // [m][c]
    __shared__ __align__(16) float Qs [32 * 68];   // [m][j]
    __shared__ __align__(16) float KVs[32 * 256];  // [m][c]
    __shared__ float ksE[32];

    const int t    = threadIdx.x;
    const int b    = blockIdx.x >> 6;
    const int tile = blockIdx.x & 63;
    const int n0   = tile << 8;
    const float* xb = x + (size_t)b * NC * NN;
    const float g = gamma[0];

    #pragma unroll
    for (int i = 0; i < 16; ++i) {
        int f = t + (i << 9);
        wqM[(f >> 8) * 260 + (f & 255)] = wq[f];
        KVs[f] = kv[(size_t)b * 8192 + f];
    }
    if (t < 32) ksE[t] = ksum[b * 32 + t] + EPSF;

    const int jsQ = t & 15;        // Q-compute: 4 j's at 4*jsQ
    const int mQ  = t >> 4;        // Q-compute: m
    const float bqm = bq[mQ];
    const int jO  = t & 63;        // out-phase: column
    const int c0O = (t >> 6) << 5; // out-phase: 32 c's

    for (int st = 0; st < 4; ++st) {
        const int n1 = n0 + (st << 6);
        __syncthreads();  // xs free (covers wqM/KVs/ksE on st=0)
        #pragma unroll
        for (int i = 0; i < 32; ++i) {
            int f = t + (i << 9);
            int c = f >> 6, j = f & 63;
            xs[f] = xb[c * NN + n1 + j];
        }
        __syncthreads();

        // --- Q compute: Q[mQ][4jsQ..+3] ---
        float qa[4] = {0.f, 0.f, 0.f, 0.f};
        #pragma unroll 4
        for (int c = 0; c < 256; c += 4) {
            float4 w  = *(const float4*)&wqM[mQ * 260 + c];
            float4 x0 = *(const float4*)&xs[(c + 0) * 64 + (jsQ << 2)];
            float4 x1 = *(const float4*)&xs[(c + 1) * 64 + (jsQ << 2)];
            float4 x2 = *(const float4*)&xs[(c + 2) * 64 + (jsQ << 2)];
            float4 x3 = *(const float4*)&xs[(c + 3) * 64 + (jsQ << 2)];
            qa[0] = fmaf(w.x, x0.x, qa[0]); qa[0] = fmaf(w.y, x1.x, qa[0]);
            qa[0] = fmaf(w.z, x2.x, qa[0]); qa[0] = fmaf(w.w, x3.x, qa[0]);
            qa[1] = fmaf(w.x, x0.y, qa[1]); qa[1] = fmaf(w.y, x1.y, qa[1]);
            qa[1] = fmaf(w.z, x2.y, qa[1]); qa[1] = fmaf(w.w, x3.y, qa[1]);
            qa[2] = fmaf(w.x, x0.z, qa[2]); qa[2] = fmaf(w.y, x1.z, qa[2]);
            qa[2] = fmaf(w.z, x2.z, qa[2]); qa[2] = fmaf(w.w, x3.z, qa[2]);
            qa[3] = fmaf(w.x, x0.w, qa[3]); qa[3] = fmaf(w.y, x1.w, qa[3]);
            qa[3] = fmaf(w.z, x2.w, qa[3]); qa[3] = fmaf(w.w, x3.w, qa[3]);
        }
        #pragma unroll
        for (int r = 0; r < 4; ++r)
            Qs[mQ * 68 + (jsQ << 2) + r] = softplusf(qa[r] + bqm);
        __syncthreads();

        // --- out phase ---
        float q[32];
        #pragma unroll
        for (int m = 0; m < 32; ++m) q[m] = Qs[m * 68 + jO];
        float den = 0.f;
        #pragma unroll
        for (int m = 0; m < 32; ++m) den = fmaf(q[m], ksE[m], den);
        const float nrm = g / den;

        #pragma unroll
        for (int cc = 0; cc < 8; ++cc) {
            const int c = c0O + (cc << 2);
            float s0 = 0.f, s1 = 0.f, s2 = 0.f, s3 = 0.f;
            #pragma unroll
            for (int m = 0; m < 32; ++m) {
                float4 kvv = *(const float4*)&KVs[m * 256 + c];  // wave-uniform
                s0 = fmaf(q[m], kvv.x, s0);
                s1 = fmaf(q[m], kvv.y, s1);
                s2 = fmaf(q[m], kvv.z, s2);
                s3 = fmaf(q[m], kvv.w, s3);
            }
            size_t base = (size_t)b * NC * NN + (size_t)c * NN + n1 + jO;
            out[base         ] = xs[(c + 0) * 64 + jO] + nrm * s0;
            out[base +     NN] = xs[(c + 1) * 64 + jO] + nrm * s1;
            out[base + 2 * NN] = xs[(c + 2) * 64 + jO] + nrm * s2;
            out[base + 3 * NN] = xs[(c + 3) * 64 + jO] + nrm * s3;
        }
    }
}

// ---------------------------------------------------------------------------
extern "C" void kernel_launch(void* const* d_in, const int* in_sizes, int n_in,
                              void* d_out, int out_size, void* d_ws, size_t ws_size,
                              hipStream_t stream)
{
    (void)in_sizes; (void)n_in; (void)out_size;
    const float* x     = (const float*)d_in[0];
    const float* wq    = (const float*)d_in[1];
    const float* bq    = (const float*)d_in[2];
    const float* wk    = (const float*)d_in[3];
    const float* bk    = (const float*)d_in[4];
    const float* wv    = (const float*)d_in[5];
    const float* bv    = (const float*)d_in[6];
    const float* gamma = (const float*)d_in[7];
    float* out = (float*)d_out;

    char* ws = (char*)d_ws;
    float* kxf  = (float*)(ws);              // 8*8192 floats   = 262144 B
    float* ksum = (float*)(ws + 262144);     // 256 floats      = 1024 B
    float* kv   = (float*)(ws + 263168);     // 8*8192 floats   = 262144 B
    float* part = (float*)(ws + 525312);     // 512*8192 floats = 16 MB (optional)
    const size_t need_part = 525312ull + 512ull * 8192ull * 4ull;
    const int use_part = (ws_size >= need_part) ? 1 : 0;

    hipMemsetAsync(ksum, 0, 1024, stream);
    if (!use_part) hipMemsetAsync(kxf, 0, 262144, stream);

    kA<<<dim3(512), dim3(256), 0, stream>>>(x, wk, bk, part, kxf, ksum, use_part);
    if (use_part) kR<<<dim3(256), dim3(256), 0, stream>>>(part, kxf);
    kB<<<dim3(64), dim3(256), 0, stream>>>(kxf, ksum, wv, bv, kv);
    kC<<<dim3(512), dim3(512), 0, stream>>>(x, wq, bq, kv, ksum, gamma, out);
}